// Round 10
// baseline (62.138 us; speedup 1.0000x reference)
//
#include <hip/hip_runtime.h>
#include <math.h>

#define NBC   16          // b*2
#define NF    160
#define NT    1000
#define TS    32          // sites per block
#define JW    48          // staged Q columns (3 MFMA subtiles)
#define QSTR  49          // Qlds row stride

typedef __attribute__((ext_vector_type(8))) short short8;
typedef __attribute__((ext_vector_type(4))) float f32x4;

static __device__ __forceinline__ short f2bf(float x) {
    unsigned u = __builtin_bit_cast(unsigned, x);
    unsigned r = (u + 0x7fffu + ((u >> 16) & 1u)) >> 16;
    return (short)r;
}
static __device__ __forceinline__ float bf2f(short s) {
    unsigned u = ((unsigned)(unsigned short)s) << 16;
    return __builtin_bit_cast(float, u);
}

// ---------------------------------------------------------------------------
// k13 v2: fused qproj(MFMA split-bf16)+LN+key/score/softmax, TS=32, 640 thr
// (10 waves), ~75 KB LDS -> 2 blocks/CU for cross-block phase overlap.
// Staging writes bf16 hi/lo fragments DIRECTLY (no fp32 Xs, no convert pass).
//   ph1: far cols tq=t0-3..t0+44 -> Bhi/Blo fragments (15 slots)
//   ph2: all 10 waves MFMA (A=ql_w in VGPRs) -> LN -> Qlds[160][49]
//   ph3: per-lane-site scores, f split 20 groups x 8 (wave, half)
//   ph4: reduce 20 groups + quadrant softmax -> W
// ---------------------------------------------------------------------------
__global__ __launch_bounds__(640, 5) void k13_fused(const float* __restrict__ far,
                                                    const float* __restrict__ mix,
                                                    const float* __restrict__ qlw,
                                                    const float* __restrict__ qlb,
                                                    const float* __restrict__ qng,
                                                    const float* __restrict__ qnb,
                                                    const float* __restrict__ qvec,
                                                    const float* __restrict__ kcw,
                                                    const float* __restrict__ kcb,
                                                    const float* __restrict__ klw,
                                                    const float* __restrict__ klb,
                                                    const float* __restrict__ kng,
                                                    const float* __restrict__ knb,
                                                    const float* __restrict__ kvec,
                                                    float* __restrict__ W) {
    __shared__ float pool[18720];      // 74.9 KB total
    __shared__ float lnM[48], lnI[48];
    float* Qlds = pool;                        // [160][49], persistent ph2->ph3
    float* regB = pool + 7840;                 // 10880 floats, phase-aliased
    short* Bhi  = (short*)regB;                // 15 slots x 64 x 8 shorts
    short* Blo  = Bhi + 7680;
    float* redS = regB;                        // [48][41] (after frags dead)
    float* redQ = regB + 1968;
    float* sbuf = regB;                        // [20][32][17] (after red dead)

    const int bc = blockIdx.x;
    const int t0 = blockIdx.y * TS;
    const int tid = threadIdx.x;
    const int w = __builtin_amdgcn_readfirstlane(tid >> 6);  // 0..9
    const int l = tid & 63;
    const int b = bc >> 1, c = bc & 1;
    const float sgn = c ? -1.f : 1.f;
    const float* Xb = far + (size_t)bc * NF * NT;
    const int row = l & 15;      // A row / D col
    const int kb = l >> 4;       // k-block 0..3

    // ---- A fragments (ql_w rows, 16 fo per wave), hi/lo bf16 ----
    short8 Ahi[5], Alo[5];
    #pragma unroll
    for (int fc = 0; fc < 5; ++fc) {
        const float* ap = qlw + (size_t)(16 * w + row) * NF + fc * 32 + kb * 8;
        float4 x0 = *(const float4*)(ap + 0);
        float4 x1 = *(const float4*)(ap + 4);
        float xv[8] = {x0.x, x0.y, x0.z, x0.w, x1.x, x1.y, x1.z, x1.w};
        short8 h, lo;
        #pragma unroll
        for (int j = 0; j < 8; ++j) {
            short hj = f2bf(xv[j]);
            h[j] = hj;
            lo[j] = f2bf(xv[j] - bf2f(hj));
        }
        Ahi[fc] = h; Alo[fc] = lo;
    }

    // ---- phase 1: stage far -> fragments directly (160 x 48 elems) ----
    #pragma unroll
    for (int i = 0; i < 12; ++i) {
        int o = tid + i * 640;           // 0..7679
        int fi = o / JW, j = o - fi * JW;
        int tq = t0 - 3 + j;
        float v = (tq >= 0 && tq < NT) ? Xb[fi * NT + tq] * sgn : 0.f;
        short hi = f2bf(v);
        short lo = f2bf(v - bf2f(hi));
        int slot = (j >> 4) * 5 + (fi >> 5);          // tt*5 + fc
        int sl = (((fi & 31) >> 3) << 4) | (j & 15);  // fragment lane
        int idx = (slot * 64 + sl) * 8 + (fi & 7);
        Bhi[idx] = hi;
        Blo[idx] = lo;
    }
    __syncthreads();

    // ---- phase 2: MFMA (all 10 waves, 3 t-subtiles each) ----
    f32x4 acc0 = {0.f, 0.f, 0.f, 0.f}, acc1 = acc0, acc2 = acc0;
    #pragma unroll
    for (int fc = 0; fc < 5; ++fc) {
        #pragma unroll
        for (int tt = 0; tt < 3; ++tt) {
            short8 bh = *(const short8*)&Bhi[((tt * 5 + fc) * 64 + l) * 8];
            short8 bl = *(const short8*)&Blo[((tt * 5 + fc) * 64 + l) * 8];
            f32x4 a = (tt == 0) ? acc0 : (tt == 1) ? acc1 : acc2;
            a = __builtin_amdgcn_mfma_f32_16x16x32_bf16(Ahi[fc], bh, a, 0, 0, 0);
            a = __builtin_amdgcn_mfma_f32_16x16x32_bf16(Ahi[fc], bl, a, 0, 0, 0);
            a = __builtin_amdgcn_mfma_f32_16x16x32_bf16(Alo[fc], bh, a, 0, 0, 0);
            if (tt == 0) acc0 = a; else if (tt == 1) acc1 = a; else acc2 = a;
        }
    }
    __syncthreads();   // fragments dead; regB becomes red

    float qlbv[4], gam[4], bet[4];
    #pragma unroll
    for (int r = 0; r < 4; ++r) {
        int fo = 16 * w + kb * 4 + r;
        qlbv[r] = qlb[fo];
        float sq = 1.f / (1.f + expf(-qvec[fo]));
        gam[r] = qng[fo] * sq;
        bet[r] = qnb[fo] * sq;
    }
    #pragma unroll
    for (int tt = 0; tt < 3; ++tt) {
        f32x4 a = (tt == 0) ? acc0 : (tt == 1) ? acc1 : acc2;
        float v0 = a[0] + qlbv[0], v1 = a[1] + qlbv[1];
        float v2 = a[2] + qlbv[2], v3 = a[3] + qlbv[3];
        int j = tt * 16 + row;
        redS[j * 41 + w * 4 + kb] = v0 + v1 + v2 + v3;
        redQ[j * 41 + w * 4 + kb] = v0 * v0 + v1 * v1 + v2 * v2 + v3 * v3;
    }
    __syncthreads();

    if (tid < 48) {
        float s = 0.f, q = 0.f;
        #pragma unroll 8
        for (int j = 0; j < 40; ++j) {
            s += redS[tid * 41 + j];
            q += redQ[tid * 41 + j];
        }
        float mean = s * (1.f / NF);
        float var = q * (1.f / NF) - mean * mean;
        lnM[tid] = mean;
        lnI[tid] = 1.f / sqrtf(var + 1e-5f);
    }
    __syncthreads();

    #pragma unroll
    for (int tt = 0; tt < 3; ++tt) {
        f32x4 a = (tt == 0) ? acc0 : (tt == 1) ? acc1 : acc2;
        int j = tt * 16 + row;
        float mean = lnM[j], inv = lnI[j];
        #pragma unroll
        for (int r = 0; r < 4; ++r) {
            int fo = 16 * w + kb * 4 + r;
            float v = a[r] + qlbv[r];
            Qlds[fo * QSTR + j] = (v - mean) * inv * gam[r] + bet[r];
        }
    }
    __syncthreads();   // Qlds ready; red dead -> sbuf

    // ---- phase 3: per-lane-site scores (group g = w*2+h owns 8 f) ----
    float kw0[4], kw1[4], kbv[4], klwm[16], klbv[4], kngv[4], knbv[4], sigk[4];
    #pragma unroll
    for (int j = 0; j < 4; ++j) {
        kw0[j] = kcw[(4 * c + j) * 2 + 0];
        kw1[j] = kcw[(4 * c + j) * 2 + 1];
        kbv[j] = kcb[4 * c + j];
        klbv[j] = klb[j];
        kngv[j] = kng[j];
        knbv[j] = knb[j];
        sigk[j] = 0.5f / (1.f + expf(-kvec[j]));   // sigmoid(k_vec)/sqrt(k)
    }
    #pragma unroll
    for (int x = 0; x < 16; ++x) klwm[x] = klw[x];

    const int site = l & 31;
    const int h = l >> 5;
    const int t = t0 + site;
    const bool valid = t < NT;

    float s[16];
    #pragma unroll
    for (int x = 0; x < 16; ++x) s[x] = 0.f;

    const float* mix0 = mix + (size_t)(b * 2) * NF * NT;
    const float* mix1 = mix0 + (size_t)NF * NT;
    const int f0 = w * 16 + h * 8;

    if (valid) {
        #pragma unroll
        for (int ff = 0; ff < 8; ++ff) {
            int f = f0 + ff;
            float m0 = mix0[(size_t)f * NT + t];
            float m1 = mix1[(size_t)f * NT + t];
            float kraw[4], klin[4];
            #pragma unroll
            for (int j = 0; j < 4; ++j)
                kraw[j] = fmaf(kw0[j], m0, fmaf(kw1[j], m1, kbv[j]));
            #pragma unroll
            for (int jo = 0; jo < 4; ++jo) {
                float a = klbv[jo];
                #pragma unroll
                for (int ji = 0; ji < 4; ++ji) a = fmaf(klwm[jo * 4 + ji], kraw[ji], a);
                klin[jo] = a;
            }
            float mn = 0.25f * (klin[0] + klin[1] + klin[2] + klin[3]);
            float d0 = klin[0] - mn, d1 = klin[1] - mn, d2 = klin[2] - mn, d3 = klin[3] - mn;
            float var = 0.25f * (d0 * d0 + d1 * d1 + d2 * d2 + d3 * d3);
            float inv = 1.f / sqrtf(var + 1e-5f);
            float kn[4];
            kn[0] = (d0 * inv * kngv[0] + knbv[0]) * sigk[0];
            kn[1] = (d1 * inv * kngv[1] + knbv[1]) * sigk[1];
            kn[2] = (d2 * inv * kngv[2] + knbv[2]) * sigk[2];
            kn[3] = (d3 * inv * kngv[3] + knbv[3]) * sigk[3];

            float q0 = Qlds[f * QSTR + site + 0];
            float q1 = Qlds[f * QSTR + site + 1];
            float q2 = Qlds[f * QSTR + site + 2];
            float q3 = Qlds[f * QSTR + site + 3];
            #pragma unroll
            for (int j = 0; j < 4; ++j) {
                s[0 * 4 + j] = fmaf(q0, kn[j], s[0 * 4 + j]);
                s[1 * 4 + j] = fmaf(q1, kn[j], s[1 * 4 + j]);
                s[2 * 4 + j] = fmaf(q2, kn[j], s[2 * 4 + j]);
                s[3 * 4 + j] = fmaf(q3, kn[j], s[3 * 4 + j]);
            }
        }
    }

    // park partials: sbuf[((w*2+h)*32 + site)*17 + x]
    {
        float* dst = &sbuf[((w * 2 + h) * 32 + site) * 17];
        #pragma unroll
        for (int q4 = 0; q4 < 4; ++q4) {
            float4 v = {s[q4 * 4 + 0], s[q4 * 4 + 1], s[q4 * 4 + 2], s[q4 * 4 + 3]};
            *(float4*)(dst + q4 * 4) = v;
        }
    }
    __syncthreads();

    // ---- phase 4: reduce 20 groups + quadrant softmax + W write ----
    if (tid < 128) {
        int q4 = tid >> 5;
        int ln = tid & 31;
        int tt = t0 + ln;
        if (tt < NT) {
            float4 a = *(const float4*)&sbuf[(0 * 32 + ln) * 17 + q4 * 4];
            #pragma unroll
            for (int g = 1; g < 20; ++g) {
                float4 p = *(const float4*)&sbuf[(g * 32 + ln) * 17 + q4 * 4];
                a.x += p.x; a.y += p.y; a.z += p.z; a.w += p.w;
            }
            float mx = fmaxf(fmaxf(a.x, a.y), fmaxf(a.z, a.w));
            float e0 = expf(a.x - mx), e1 = expf(a.y - mx);
            float e2 = expf(a.z - mx), e3 = expf(a.w - mx);
            float inv = 1.f / (e0 + e1 + e2 + e3);
            float4 v = {e0 * inv, e1 * inv, e2 * inv, e3 * inv};
            *(float4*)(W + ((size_t)bc * NT + tt) * 16 + q4 * 4) = v;
        }
    }
}

// ---------------------------------------------------------------------------
// complex 4x4 solve, partial pivoting (cabs1), fully unrolled
// ---------------------------------------------------------------------------
__device__ __forceinline__ void csolve4(float Ar[16], float Ai[16],
                                        float br[4], float bi[4],
                                        float wr[4], float wi[4]) {
    #pragma unroll
    for (int col = 0; col < 4; ++col) {
        #pragma unroll
        for (int r = col + 1; r < 4; ++r) {
            float cp = fabsf(Ar[col * 4 + col]) + fabsf(Ai[col * 4 + col]);
            float cr = fabsf(Ar[r * 4 + col]) + fabsf(Ai[r * 4 + col]);
            bool sw = cr > cp;
            #pragma unroll
            for (int m = col; m < 4; ++m) {
                float a0 = Ar[col * 4 + m], a1 = Ar[r * 4 + m];
                Ar[col * 4 + m] = sw ? a1 : a0;
                Ar[r * 4 + m]   = sw ? a0 : a1;
                float c0 = Ai[col * 4 + m], c1 = Ai[r * 4 + m];
                Ai[col * 4 + m] = sw ? c1 : c0;
                Ai[r * 4 + m]   = sw ? c0 : c1;
            }
            float b0 = br[col], b1 = br[r];
            br[col] = sw ? b1 : b0; br[r] = sw ? b0 : b1;
            float d0 = bi[col], d1 = bi[r];
            bi[col] = sw ? d1 : d0; bi[r] = sw ? d0 : d1;
        }
        float pr = Ar[col * 4 + col], pi = Ai[col * 4 + col];
        float den = 1.f / (pr * pr + pi * pi);
        #pragma unroll
        for (int r = col + 1; r < 4; ++r) {
            float nr = Ar[r * 4 + col], ni = Ai[r * 4 + col];
            float fr = (nr * pr + ni * pi) * den;
            float fi = (ni * pr - nr * pi) * den;
            #pragma unroll
            for (int m = col + 1; m < 4; ++m) {
                float tr = Ar[col * 4 + m], ti = Ai[col * 4 + m];
                Ar[r * 4 + m] -= fr * tr - fi * ti;
                Ai[r * 4 + m] -= fr * ti + fi * tr;
            }
            float tr = br[col], ti = bi[col];
            br[r] -= fr * tr - fi * ti;
            bi[r] -= fr * ti + fi * tr;
        }
    }
    #pragma unroll
    for (int col = 3; col >= 0; --col) {
        float sr = br[col], si = bi[col];
        #pragma unroll
        for (int m = col + 1; m < 4; ++m) {
            float tr = Ar[col * 4 + m], ti = Ai[col * 4 + m];
            sr -= tr * wr[m] - ti * wi[m];
            si -= tr * wi[m] + ti * wr[m];
        }
        float pr = Ar[col * 4 + col], pi = Ai[col * 4 + col];
        float den = 1.f / (pr * pr + pi * pi);
        wr[col] = (sr * pr + si * pi) * den;
        wi[col] = (si * pr - sr * pi) * den;
    }
}

// ---------------------------------------------------------------------------
// k4: per (b,f,t): build rank-1 value/out, assemble A,rhs, solve, Wiener sum
// ---------------------------------------------------------------------------
__global__ __launch_bounds__(256) void k4_final(const float* __restrict__ far,
                                                const float* __restrict__ mix,
                                                const float* __restrict__ Wt,
                                                const float* __restrict__ vvec,
                                                float* __restrict__ out) {
    const int t = blockIdx.x * 256 + threadIdx.x;
    const int f = blockIdx.y;
    const int b = blockIdx.z;
    if (t >= NT) return;

    const float* fr  = far + (size_t)(b * 2 + 0) * NF * NT + (size_t)f * NT;
    const float* fim = far + (size_t)(b * 2 + 1) * NF * NT + (size_t)f * NT;
    float ur[4], ui[4];
    #pragma unroll
    for (int d = 0; d < 4; ++d) {
        int tp = t - 3 + d;
        bool ok = tp >= 0;
        ur[d] = ok ? fr[tp] : 0.f;
        ui[d] = ok ? fim[tp] : 0.f;
    }
    float m0 = mix[(size_t)(b * 2 + 0) * NF * NT + (size_t)f * NT + t];
    float m1 = mix[(size_t)(b * 2 + 1) * NF * NT + (size_t)f * NT + t];

    float sv[4];
    #pragma unroll
    for (int i = 0; i < 4; ++i) sv[i] = 1.f / (1.f + expf(-vvec[i]));

    const float* w0p = Wt + ((size_t)(b * 2 + 0) * NT + t) * 16;
    const float* w1p = Wt + ((size_t)(b * 2 + 1) * NT + t) * 16;

    float g0[4], g1[4];
    #pragma unroll
    for (int j = 0; j < 4; ++j) { g0[j] = 0.f; g1[j] = 0.f; }
    #pragma unroll
    for (int i = 0; i < 4; ++i) {
        float a0 = ur[i] * sv[i];
        float a1 = -ui[i] * sv[i];
        #pragma unroll
        for (int j = 0; j < 4; ++j) {
            g0[j] = fmaf(a0, w0p[i * 4 + j], g0[j]);
            g1[j] = fmaf(a1, w1p[i * 4 + j], g1[j]);
        }
    }

    float Ar[16], Ai[16], br[4], bi[4], wr[4], wi[4];
    #pragma unroll
    for (int j = 0; j < 4; ++j) {
        #pragma unroll
        for (int m = 0; m < 4; ++m) {
            float e = (j == m) ? (1.0f + 1e-8f) : 1e-8f;
            Ar[j * 4 + m] = fmaf(ur[m], g0[j], e);
            Ai[j * 4 + m] = fmaf(-ui[m], g1[j], e);
        }
        br[j] = m0 * g0[j];
        bi[j] = m1 * g1[j];
    }

    csolve4(Ar, Ai, br, bi, wr, wi);

    float resr = 0.f, resi = 0.f;
    #pragma unroll
    for (int d = 0; d < 4; ++d) {
        resr += ur[d] * wr[d] - ui[d] * wi[d];
        resi += ur[d] * wi[d] + ui[d] * wr[d];
    }
    out[(size_t)(b * 2 + 0) * NF * NT + (size_t)f * NT + t] = resr;
    out[(size_t)(b * 2 + 1) * NF * NT + (size_t)f * NT + t] = resi;
}

// ---------------------------------------------------------------------------
extern "C" void kernel_launch(void* const* d_in, const int* in_sizes, int n_in,
                              void* d_out, int out_size, void* d_ws, size_t ws_size,
                              hipStream_t stream) {
    const float* far  = (const float*)d_in[0];
    const float* mix  = (const float*)d_in[1];
    const float* kcw  = (const float*)d_in[2];
    const float* kcb  = (const float*)d_in[3];
    const float* qlw  = (const float*)d_in[4];
    const float* qlb  = (const float*)d_in[5];
    const float* qng  = (const float*)d_in[6];
    const float* qnb  = (const float*)d_in[7];
    const float* klw  = (const float*)d_in[8];
    const float* klb  = (const float*)d_in[9];
    const float* kng  = (const float*)d_in[10];
    const float* knb  = (const float*)d_in[11];
    const float* qvec = (const float*)d_in[12];
    const float* kvec = (const float*)d_in[13];
    const float* vvec = (const float*)d_in[14];

    float* W = (float*)d_ws;                 // 16*1000*16 floats
    float* out = (float*)d_out;

    k13_fused<<<dim3(NBC, (NT + TS - 1) / TS), 640, 0, stream>>>(
        far, mix, qlw, qlb, qng, qnb, qvec, kcw, kcb, klw, klb, kng, knb, kvec, W);
    k4_final<<<dim3(4, NF, 8), 256, 0, stream>>>(far, mix, W, vvec, out);
}

// Round 11
// 52.485 us; speedup vs baseline: 1.1839x; 1.1839x over previous
//
#include <hip/hip_runtime.h>
#include <math.h>

#define NBC   16          // b*2
#define NF    160
#define NT    1000
#define TS    64          // sites per block
#define QSTR  81          // Qlds row stride

typedef __attribute__((ext_vector_type(8))) short short8;
typedef __attribute__((ext_vector_type(4))) float f32x4;

static __device__ __forceinline__ short f2bf(float x) {
    unsigned u = __builtin_bit_cast(unsigned, x);
    unsigned r = (u + 0x7fffu + ((u >> 16) & 1u)) >> 16;
    return (short)r;
}
static __device__ __forceinline__ float bf2f(short s) {
    unsigned u = ((unsigned)(unsigned short)s) << 16;
    return __builtin_bit_cast(float, u);
}

// ---------------------------------------------------------------------------
// k13 v3: fused qproj(MFMA)+LN+key/score/softmax. TS=64, 1024 thr (16 waves),
// ~71 KB LDS -> 2 blocks/CU. MFMA streamed over 5 fc-chunks of 32 fi with
// register-prefetch (loads for chunk fc+1 issued before chunk fc's barrier).
//   ph1 (x5): far[32 fi][80 j] -> bf16 hi/lo fragments -> 10-wave MFMA
//   ph2: LN stats (redS/redQ alias Qlds region) -> Qlds[160][81]
//   ph3: per-lane-site scores, f split 16 waves x 10; folded key pipeline
//   ph4: reduce 16 groups + quadrant softmax -> W
// ---------------------------------------------------------------------------
__global__ __launch_bounds__(1024, 4) void k13_fused(const float* __restrict__ far,
                                                     const float* __restrict__ mix,
                                                     const float* __restrict__ qlw,
                                                     const float* __restrict__ qlb,
                                                     const float* __restrict__ qng,
                                                     const float* __restrict__ qnb,
                                                     const float* __restrict__ qvec,
                                                     const float* __restrict__ kcw,
                                                     const float* __restrict__ kcb,
                                                     const float* __restrict__ klw,
                                                     const float* __restrict__ klb,
                                                     const float* __restrict__ kng,
                                                     const float* __restrict__ knb,
                                                     const float* __restrict__ kvec,
                                                     float* __restrict__ W) {
    __shared__ float pool[17600];        // 70.4 KB
    __shared__ float lnM[80], lnI[80];
    float* Qlds = pool;                          // [160][81] (ph2->ph3)
    float* redS = pool;                          // [80][41]  (aliases Qlds, pre-write)
    float* redQ = pool + 3280;
    short* Bhi  = (short*)(pool + 12960);        // 5 tt x 64 x 8 shorts (5120 B)
    short* Blo  = (short*)(pool + 14240);        // 5120 B
    float* sbuf = pool;                          // [16][64][17] (ph4, aliases all)

    const int bc = blockIdx.x;
    const int t0 = blockIdx.y * TS;
    const int tid = threadIdx.x;
    const int w = __builtin_amdgcn_readfirstlane(tid >> 6);  // 0..15
    const int l = tid & 63;
    const int b = bc >> 1, c = bc & 1;
    const float sgn = c ? -1.f : 1.f;
    const float* Xb = far + (size_t)bc * NF * NT;
    const int row = l & 15;      // A row / D col
    const int kb = l >> 4;       // k-block 0..3

    // ---- A fragments (ql_w rows, 16 fo for waves 0..9), hi/lo bf16 ----
    short8 Ahi[5], Alo[5];
    if (w < 10) {
        #pragma unroll
        for (int fc = 0; fc < 5; ++fc) {
            const float* ap = qlw + (size_t)(16 * w + row) * NF + fc * 32 + kb * 8;
            float4 x0 = *(const float4*)(ap + 0);
            float4 x1 = *(const float4*)(ap + 4);
            float xv[8] = {x0.x, x0.y, x0.z, x0.w, x1.x, x1.y, x1.z, x1.w};
            short8 h, lo;
            #pragma unroll
            for (int j = 0; j < 8; ++j) {
                short hj = f2bf(xv[j]);
                h[j] = hj;
                lo[j] = f2bf(xv[j] - bf2f(hj));
            }
            Ahi[fc] = h; Alo[fc] = lo;
        }
    }

    // ---- streamed MFMA over 5 fc chunks, register-prefetched staging ----
    f32x4 acc0 = {0.f, 0.f, 0.f, 0.f}, acc1 = acc0, acc2 = acc0, acc3 = acc0, acc4 = acc0;
    float vcur0 = 0.f, vcur1 = 0.f, vcur2 = 0.f;

    // prefetch fc = 0
    #pragma unroll
    for (int i = 0; i < 3; ++i) {
        int e = tid + i * 1024;
        if (e < 2560) {
            int fi_l = e / 80, j = e - fi_l * 80;
            int tq = t0 - 3 + j;
            float v = (tq >= 0 && tq < NT) ? Xb[(size_t)fi_l * NT + tq] * sgn : 0.f;
            if (i == 0) vcur0 = v; else if (i == 1) vcur1 = v; else vcur2 = v;
        }
    }

    #pragma unroll
    for (int fc = 0; fc < 5; ++fc) {
        // write current chunk's fragments
        #pragma unroll
        for (int i = 0; i < 3; ++i) {
            int e = tid + i * 1024;
            if (e < 2560) {
                int fi_l = e / 80, j = e - fi_l * 80;
                int tt = j >> 4;
                int sl = ((fi_l >> 3) << 4) | (j & 15);
                int idx = (tt * 64 + sl) * 8 + (fi_l & 7);
                float v = (i == 0) ? vcur0 : (i == 1) ? vcur1 : vcur2;
                short hi = f2bf(v);
                Bhi[idx] = hi;
                Blo[idx] = f2bf(v - bf2f(hi));
            }
        }
        // issue next chunk's loads (hide HBM under MFMA + barriers)
        float vn0 = 0.f, vn1 = 0.f, vn2 = 0.f;
        if (fc < 4) {
            #pragma unroll
            for (int i = 0; i < 3; ++i) {
                int e = tid + i * 1024;
                if (e < 2560) {
                    int fi_l = e / 80, j = e - fi_l * 80;
                    int tq = t0 - 3 + j;
                    int fi = (fc + 1) * 32 + fi_l;
                    float v = (tq >= 0 && tq < NT) ? Xb[(size_t)fi * NT + tq] * sgn : 0.f;
                    if (i == 0) vn0 = v; else if (i == 1) vn1 = v; else vn2 = v;
                }
            }
        }
        __syncthreads();
        if (w < 10) {
            #pragma unroll
            for (int tt = 0; tt < 5; ++tt) {
                short8 bh = *(const short8*)&Bhi[(tt * 64 + l) * 8];
                short8 bl = *(const short8*)&Blo[(tt * 64 + l) * 8];
                f32x4 a = (tt == 0) ? acc0 : (tt == 1) ? acc1 : (tt == 2) ? acc2 : (tt == 3) ? acc3 : acc4;
                a = __builtin_amdgcn_mfma_f32_16x16x32_bf16(Ahi[fc], bh, a, 0, 0, 0);
                a = __builtin_amdgcn_mfma_f32_16x16x32_bf16(Ahi[fc], bl, a, 0, 0, 0);
                a = __builtin_amdgcn_mfma_f32_16x16x32_bf16(Alo[fc], bh, a, 0, 0, 0);
                if (tt == 0) acc0 = a; else if (tt == 1) acc1 = a; else if (tt == 2) acc2 = a;
                else if (tt == 3) acc3 = a; else acc4 = a;
            }
        }
        __syncthreads();   // fragments consumed; safe to overwrite next iter
        vcur0 = vn0; vcur1 = vn1; vcur2 = vn2;
    }

    // ---- LN stats (red arrays alias Qlds region, which is garbage so far) ----
    float qlbv[4], gam[4], bet[4];
    if (w < 10) {
        #pragma unroll
        for (int r = 0; r < 4; ++r) {
            int fo = 16 * w + kb * 4 + r;
            qlbv[r] = qlb[fo];
            float sq = 1.f / (1.f + expf(-qvec[fo]));
            gam[r] = qng[fo] * sq;
            bet[r] = qnb[fo] * sq;
        }
        #pragma unroll
        for (int tt = 0; tt < 5; ++tt) {
            f32x4 a = (tt == 0) ? acc0 : (tt == 1) ? acc1 : (tt == 2) ? acc2 : (tt == 3) ? acc3 : acc4;
            float v0 = a[0] + qlbv[0], v1 = a[1] + qlbv[1];
            float v2 = a[2] + qlbv[2], v3 = a[3] + qlbv[3];
            int j = tt * 16 + row;
            redS[j * 41 + w * 4 + kb] = v0 + v1 + v2 + v3;
            redQ[j * 41 + w * 4 + kb] = v0 * v0 + v1 * v1 + v2 * v2 + v3 * v3;
        }
    }
    __syncthreads();

    if (tid < 80) {
        float s = 0.f, q = 0.f;
        #pragma unroll 8
        for (int j = 0; j < 40; ++j) {
            s += redS[tid * 41 + j];
            q += redQ[tid * 41 + j];
        }
        float mean = s * (1.f / NF);
        float var = q * (1.f / NF) - mean * mean;
        lnM[tid] = mean;
        lnI[tid] = 1.f / sqrtf(var + 1e-5f);
    }
    __syncthreads();

    if (w < 10) {
        #pragma unroll
        for (int tt = 0; tt < 5; ++tt) {
            f32x4 a = (tt == 0) ? acc0 : (tt == 1) ? acc1 : (tt == 2) ? acc2 : (tt == 3) ? acc3 : acc4;
            int j = tt * 16 + row;
            float mean = lnM[j], inv = lnI[j];
            #pragma unroll
            for (int r = 0; r < 4; ++r) {
                int fo = 16 * w + kb * 4 + r;
                float v = a[r] + qlbv[r];
                Qlds[fo * QSTR + j] = (v - mean) * inv * gam[r] + bet[r];
            }
        }
    }
    __syncthreads();   // Qlds ready

    // ---- phase 3: folded key pipeline + scores (wave w: f in [10w,10w+10)) ----
    // klin = klw@(kcw_c@[m0;m1]+kcb_c)+klb folded to M0/M1/B; centering absorbed:
    // d_j = alpha_j*m0 + beta_j*m1 + gamm_j;  kn_j = (d_j*inv)*G_j + H_j
    float alpha[4], beta4[4], gamm[4], G[4], H[4];
    {
        float M0[4], M1[4], B4[4];
        #pragma unroll
        for (int jo = 0; jo < 4; ++jo) {
            float m0 = 0.f, m1 = 0.f, bb = klb[jo];
            #pragma unroll
            for (int ji = 0; ji < 4; ++ji) {
                float kl = klw[jo * 4 + ji];
                m0 = fmaf(kl, kcw[(4 * c + ji) * 2 + 0], m0);
                m1 = fmaf(kl, kcw[(4 * c + ji) * 2 + 1], m1);
                bb = fmaf(kl, kcb[4 * c + ji], bb);
            }
            M0[jo] = m0; M1[jo] = m1; B4[jo] = bb;
        }
        float am = 0.25f * (M0[0] + M0[1] + M0[2] + M0[3]);
        float bm = 0.25f * (M1[0] + M1[1] + M1[2] + M1[3]);
        float cm = 0.25f * (B4[0] + B4[1] + B4[2] + B4[3]);
        #pragma unroll
        for (int jo = 0; jo < 4; ++jo) {
            alpha[jo] = M0[jo] - am;
            beta4[jo] = M1[jo] - bm;
            gamm[jo]  = B4[jo] - cm;
            float sk = 0.5f / (1.f + expf(-kvec[jo]));   // sigmoid/sqrt(k)
            G[jo] = kng[jo] * sk;
            H[jo] = knb[jo] * sk;
        }
    }

    const int t = t0 + l;
    const bool valid = t < NT;

    float s[16];
    #pragma unroll
    for (int x = 0; x < 16; ++x) s[x] = 0.f;

    const float* mix0 = mix + (size_t)(b * 2) * NF * NT;
    const float* mix1 = mix0 + (size_t)NF * NT;
    const int f0 = w * 10;

    if (valid) {
        #pragma unroll
        for (int ff = 0; ff < 10; ++ff) {
            int f = f0 + ff;
            float m0 = mix0[(size_t)f * NT + t];
            float m1 = mix1[(size_t)f * NT + t];
            float d0 = fmaf(alpha[0], m0, fmaf(beta4[0], m1, gamm[0]));
            float d1 = fmaf(alpha[1], m0, fmaf(beta4[1], m1, gamm[1]));
            float d2 = fmaf(alpha[2], m0, fmaf(beta4[2], m1, gamm[2]));
            float d3 = fmaf(alpha[3], m0, fmaf(beta4[3], m1, gamm[3]));
            float var = 0.25f * (d0 * d0 + d1 * d1 + d2 * d2 + d3 * d3);
            float inv = 1.f / sqrtf(var + 1e-5f);
            float kn[4];
            kn[0] = fmaf(d0 * inv, G[0], H[0]);
            kn[1] = fmaf(d1 * inv, G[1], H[1]);
            kn[2] = fmaf(d2 * inv, G[2], H[2]);
            kn[3] = fmaf(d3 * inv, G[3], H[3]);

            float q0 = Qlds[f * QSTR + l + 0];
            float q1 = Qlds[f * QSTR + l + 1];
            float q2 = Qlds[f * QSTR + l + 2];
            float q3 = Qlds[f * QSTR + l + 3];
            #pragma unroll
            for (int j = 0; j < 4; ++j) {
                s[0 * 4 + j] = fmaf(q0, kn[j], s[0 * 4 + j]);
                s[1 * 4 + j] = fmaf(q1, kn[j], s[1 * 4 + j]);
                s[2 * 4 + j] = fmaf(q2, kn[j], s[2 * 4 + j]);
                s[3 * 4 + j] = fmaf(q3, kn[j], s[3 * 4 + j]);
            }
        }
    }
    __syncthreads();   // all Qlds reads done before sbuf overwrites pool

    // park partials: sbuf[(w*64+l)*17 + x]
    {
        float* dst = &sbuf[(w * 64 + l) * 17];
        #pragma unroll
        for (int q4 = 0; q4 < 4; ++q4) {
            float4 v = {s[q4 * 4 + 0], s[q4 * 4 + 1], s[q4 * 4 + 2], s[q4 * 4 + 3]};
            *(float4*)(dst + q4 * 4) = v;
        }
    }
    __syncthreads();

    // ---- phase 4: reduce 16 groups + quadrant softmax + W write ----
    if (tid < 256) {
        int q4 = tid >> 6;
        int ln = tid & 63;
        int tt = t0 + ln;
        if (tt < NT) {
            float4 a = *(const float4*)&sbuf[(0 * 64 + ln) * 17 + q4 * 4];
            #pragma unroll
            for (int ww = 1; ww < 16; ++ww) {
                float4 p = *(const float4*)&sbuf[(ww * 64 + ln) * 17 + q4 * 4];
                a.x += p.x; a.y += p.y; a.z += p.z; a.w += p.w;
            }
            float mx = fmaxf(fmaxf(a.x, a.y), fmaxf(a.z, a.w));
            float e0 = expf(a.x - mx), e1 = expf(a.y - mx);
            float e2 = expf(a.z - mx), e3 = expf(a.w - mx);
            float inv = 1.f / (e0 + e1 + e2 + e3);
            float4 v = {e0 * inv, e1 * inv, e2 * inv, e3 * inv};
            *(float4*)(W + ((size_t)bc * NT + tt) * 16 + q4 * 4) = v;
        }
    }
}

// ---------------------------------------------------------------------------
// complex 4x4 solve, partial pivoting (cabs1), fully unrolled
// ---------------------------------------------------------------------------
__device__ __forceinline__ void csolve4(float Ar[16], float Ai[16],
                                        float br[4], float bi[4],
                                        float wr[4], float wi[4]) {
    #pragma unroll
    for (int col = 0; col < 4; ++col) {
        #pragma unroll
        for (int r = col + 1; r < 4; ++r) {
            float cp = fabsf(Ar[col * 4 + col]) + fabsf(Ai[col * 4 + col]);
            float cr = fabsf(Ar[r * 4 + col]) + fabsf(Ai[r * 4 + col]);
            bool sw = cr > cp;
            #pragma unroll
            for (int m = col; m < 4; ++m) {
                float a0 = Ar[col * 4 + m], a1 = Ar[r * 4 + m];
                Ar[col * 4 + m] = sw ? a1 : a0;
                Ar[r * 4 + m]   = sw ? a0 : a1;
                float c0 = Ai[col * 4 + m], c1 = Ai[r * 4 + m];
                Ai[col * 4 + m] = sw ? c1 : c0;
                Ai[r * 4 + m]   = sw ? c0 : c1;
            }
            float b0 = br[col], b1 = br[r];
            br[col] = sw ? b1 : b0; br[r] = sw ? b0 : b1;
            float d0 = bi[col], d1 = bi[r];
            bi[col] = sw ? d1 : d0; bi[r] = sw ? d0 : d1;
        }
        float pr = Ar[col * 4 + col], pi = Ai[col * 4 + col];
        float den = 1.f / (pr * pr + pi * pi);
        #pragma unroll
        for (int r = col + 1; r < 4; ++r) {
            float nr = Ar[r * 4 + col], ni = Ai[r * 4 + col];
            float fr = (nr * pr + ni * pi) * den;
            float fi = (ni * pr - nr * pi) * den;
            #pragma unroll
            for (int m = col + 1; m < 4; ++m) {
                float tr = Ar[col * 4 + m], ti = Ai[col * 4 + m];
                Ar[r * 4 + m] -= fr * tr - fi * ti;
                Ai[r * 4 + m] -= fr * ti + fi * tr;
            }
            float tr = br[col], ti = bi[col];
            br[r] -= fr * tr - fi * ti;
            bi[r] -= fr * ti + fi * tr;
        }
    }
    #pragma unroll
    for (int col = 3; col >= 0; --col) {
        float sr = br[col], si = bi[col];
        #pragma unroll
        for (int m = col + 1; m < 4; ++m) {
            float tr = Ar[col * 4 + m], ti = Ai[col * 4 + m];
            sr -= tr * wr[m] - ti * wi[m];
            si -= tr * wi[m] + ti * wr[m];
        }
        float pr = Ar[col * 4 + col], pi = Ai[col * 4 + col];
        float den = 1.f / (pr * pr + pi * pi);
        wr[col] = (sr * pr + si * pi) * den;
        wi[col] = (si * pr - sr * pi) * den;
    }
}

// ---------------------------------------------------------------------------
// k4: per (b,f,t): build rank-1 value/out, assemble A,rhs, solve, Wiener sum
// ---------------------------------------------------------------------------
__global__ __launch_bounds__(256) void k4_final(const float* __restrict__ far,
                                                const float* __restrict__ mix,
                                                const float* __restrict__ Wt,
                                                const float* __restrict__ vvec,
                                                float* __restrict__ out) {
    const int t = blockIdx.x * 256 + threadIdx.x;
    const int f = blockIdx.y;
    const int b = blockIdx.z;
    if (t >= NT) return;

    const float* fr  = far + (size_t)(b * 2 + 0) * NF * NT + (size_t)f * NT;
    const float* fim = far + (size_t)(b * 2 + 1) * NF * NT + (size_t)f * NT;
    float ur[4], ui[4];
    #pragma unroll
    for (int d = 0; d < 4; ++d) {
        int tp = t - 3 + d;
        bool ok = tp >= 0;
        ur[d] = ok ? fr[tp] : 0.f;
        ui[d] = ok ? fim[tp] : 0.f;
    }
    float m0 = mix[(size_t)(b * 2 + 0) * NF * NT + (size_t)f * NT + t];
    float m1 = mix[(size_t)(b * 2 + 1) * NF * NT + (size_t)f * NT + t];

    float sv[4];
    #pragma unroll
    for (int i = 0; i < 4; ++i) sv[i] = 1.f / (1.f + expf(-vvec[i]));

    const float* w0p = Wt + ((size_t)(b * 2 + 0) * NT + t) * 16;
    const float* w1p = Wt + ((size_t)(b * 2 + 1) * NT + t) * 16;

    float g0[4], g1[4];
    #pragma unroll
    for (int j = 0; j < 4; ++j) { g0[j] = 0.f; g1[j] = 0.f; }
    #pragma unroll
    for (int i = 0; i < 4; ++i) {
        float a0 = ur[i] * sv[i];
        float a1 = -ui[i] * sv[i];
        #pragma unroll
        for (int j = 0; j < 4; ++j) {
            g0[j] = fmaf(a0, w0p[i * 4 + j], g0[j]);
            g1[j] = fmaf(a1, w1p[i * 4 + j], g1[j]);
        }
    }

    float Ar[16], Ai[16], br[4], bi[4], wr[4], wi[4];
    #pragma unroll
    for (int j = 0; j < 4; ++j) {
        #pragma unroll
        for (int m = 0; m < 4; ++m) {
            float e = (j == m) ? (1.0f + 1e-8f) : 1e-8f;
            Ar[j * 4 + m] = fmaf(ur[m], g0[j], e);
            Ai[j * 4 + m] = fmaf(-ui[m], g1[j], e);
        }
        br[j] = m0 * g0[j];
        bi[j] = m1 * g1[j];
    }

    csolve4(Ar, Ai, br, bi, wr, wi);

    float resr = 0.f, resi = 0.f;
    #pragma unroll
    for (int d = 0; d < 4; ++d) {
        resr += ur[d] * wr[d] - ui[d] * wi[d];
        resi += ur[d] * wi[d] + ui[d] * wr[d];
    }
    out[(size_t)(b * 2 + 0) * NF * NT + (size_t)f * NT + t] = resr;
    out[(size_t)(b * 2 + 1) * NF * NT + (size_t)f * NT + t] = resi;
}

// ---------------------------------------------------------------------------
extern "C" void kernel_launch(void* const* d_in, const int* in_sizes, int n_in,
                              void* d_out, int out_size, void* d_ws, size_t ws_size,
                              hipStream_t stream) {
    const float* far  = (const float*)d_in[0];
    const float* mix  = (const float*)d_in[1];
    const float* kcw  = (const float*)d_in[2];
    const float* kcb  = (const float*)d_in[3];
    const float* qlw  = (const float*)d_in[4];
    const float* qlb  = (const float*)d_in[5];
    const float* qng  = (const float*)d_in[6];
    const float* qnb  = (const float*)d_in[7];
    const float* klw  = (const float*)d_in[8];
    const float* klb  = (const float*)d_in[9];
    const float* kng  = (const float*)d_in[10];
    const float* knb  = (const float*)d_in[11];
    const float* qvec = (const float*)d_in[12];
    const float* kvec = (const float*)d_in[13];
    const float* vvec = (const float*)d_in[14];

    float* W = (float*)d_ws;                 // 16*1000*16 floats
    float* out = (float*)d_out;

    k13_fused<<<dim3(NBC, (NT + TS - 1) / TS), 1024, 0, stream>>>(
        far, mix, qlw, qlb, qng, qnb, qvec, kcw, kcb, klw, klb, kng, knb, kvec, W);
    k4_final<<<dim3(4, NF, 8), 256, 0, stream>>>(far, mix, W, vvec, out);
}

// Round 12
// 52.460 us; speedup vs baseline: 1.1845x; 1.0005x over previous
//
#include <hip/hip_runtime.h>
#include <math.h>

#define NBC   16          // b*2
#define NF    160
#define NT    1000
#define TS    64          // sites per block
#define QSTR  81          // Qlds row stride

typedef __attribute__((ext_vector_type(8))) short short8;
typedef __attribute__((ext_vector_type(4))) float f32x4;

static __device__ __forceinline__ short f2bf(float x) {
    unsigned u = __builtin_bit_cast(unsigned, x);
    unsigned r = (u + 0x7fffu + ((u >> 16) & 1u)) >> 16;
    return (short)r;
}
static __device__ __forceinline__ float bf2f(short s) {
    unsigned u = ((unsigned)(unsigned short)s) << 16;
    return __builtin_bit_cast(float, u);
}

// ---------------------------------------------------------------------------
// k13 v4: identical to v3 EXCEPT __launch_bounds__(1024) (no min-waves arg).
// v3's (1024,4) capped VGPRs at 64, spilling the 40-VGPR A-fragment set +
// 20-VGPR accumulators to scratch -> every phase stalled on scratch reloads
// (MfmaUtil 2.4%, VALUBusy 22%). 128-VGPR budget holds everything resident.
// ---------------------------------------------------------------------------
__global__ __launch_bounds__(1024) void k13_fused(const float* __restrict__ far,
                                                  const float* __restrict__ mix,
                                                  const float* __restrict__ qlw,
                                                  const float* __restrict__ qlb,
                                                  const float* __restrict__ qng,
                                                  const float* __restrict__ qnb,
                                                  const float* __restrict__ qvec,
                                                  const float* __restrict__ kcw,
                                                  const float* __restrict__ kcb,
                                                  const float* __restrict__ klw,
                                                  const float* __restrict__ klb,
                                                  const float* __restrict__ kng,
                                                  const float* __restrict__ knb,
                                                  const float* __restrict__ kvec,
                                                  float* __restrict__ W) {
    __shared__ float pool[17600];        // 70.4 KB
    __shared__ float lnM[80], lnI[80];
    float* Qlds = pool;                          // [160][81] (ph2->ph3)
    float* redS = pool;                          // [80][41]  (aliases Qlds, pre-write)
    float* redQ = pool + 3280;
    short* Bhi  = (short*)(pool + 12960);        // 5 tt x 64 x 8 shorts (5120 B)
    short* Blo  = (short*)(pool + 14240);        // 5120 B
    float* sbuf = pool;                          // [16][64][17] (ph4, aliases all)

    const int bc = blockIdx.x;
    const int t0 = blockIdx.y * TS;
    const int tid = threadIdx.x;
    const int w = __builtin_amdgcn_readfirstlane(tid >> 6);  // 0..15
    const int l = tid & 63;
    const int b = bc >> 1, c = bc & 1;
    const float sgn = c ? -1.f : 1.f;
    const float* Xb = far + (size_t)bc * NF * NT;
    const int row = l & 15;      // A row / D col
    const int kb = l >> 4;       // k-block 0..3

    // ---- A fragments (ql_w rows, 16 fo for waves 0..9), hi/lo bf16 ----
    short8 Ahi[5], Alo[5];
    if (w < 10) {
        #pragma unroll
        for (int fc = 0; fc < 5; ++fc) {
            const float* ap = qlw + (size_t)(16 * w + row) * NF + fc * 32 + kb * 8;
            float4 x0 = *(const float4*)(ap + 0);
            float4 x1 = *(const float4*)(ap + 4);
            float xv[8] = {x0.x, x0.y, x0.z, x0.w, x1.x, x1.y, x1.z, x1.w};
            short8 h, lo;
            #pragma unroll
            for (int j = 0; j < 8; ++j) {
                short hj = f2bf(xv[j]);
                h[j] = hj;
                lo[j] = f2bf(xv[j] - bf2f(hj));
            }
            Ahi[fc] = h; Alo[fc] = lo;
        }
    }

    // ---- streamed MFMA over 5 fc chunks, register-prefetched staging ----
    f32x4 acc0 = {0.f, 0.f, 0.f, 0.f}, acc1 = acc0, acc2 = acc0, acc3 = acc0, acc4 = acc0;
    float vcur0 = 0.f, vcur1 = 0.f, vcur2 = 0.f;

    // prefetch fc = 0
    #pragma unroll
    for (int i = 0; i < 3; ++i) {
        int e = tid + i * 1024;
        if (e < 2560) {
            int fi_l = e / 80, j = e - fi_l * 80;
            int tq = t0 - 3 + j;
            float v = (tq >= 0 && tq < NT) ? Xb[(size_t)fi_l * NT + tq] * sgn : 0.f;
            if (i == 0) vcur0 = v; else if (i == 1) vcur1 = v; else vcur2 = v;
        }
    }

    #pragma unroll
    for (int fc = 0; fc < 5; ++fc) {
        // write current chunk's fragments
        #pragma unroll
        for (int i = 0; i < 3; ++i) {
            int e = tid + i * 1024;
            if (e < 2560) {
                int fi_l = e / 80, j = e - fi_l * 80;
                int tt = j >> 4;
                int sl = ((fi_l >> 3) << 4) | (j & 15);
                int idx = (tt * 64 + sl) * 8 + (fi_l & 7);
                float v = (i == 0) ? vcur0 : (i == 1) ? vcur1 : vcur2;
                short hi = f2bf(v);
                Bhi[idx] = hi;
                Blo[idx] = f2bf(v - bf2f(hi));
            }
        }
        // issue next chunk's loads (hide HBM under MFMA + barriers)
        float vn0 = 0.f, vn1 = 0.f, vn2 = 0.f;
        if (fc < 4) {
            #pragma unroll
            for (int i = 0; i < 3; ++i) {
                int e = tid + i * 1024;
                if (e < 2560) {
                    int fi_l = e / 80, j = e - fi_l * 80;
                    int tq = t0 - 3 + j;
                    int fi = (fc + 1) * 32 + fi_l;
                    float v = (tq >= 0 && tq < NT) ? Xb[(size_t)fi * NT + tq] * sgn : 0.f;
                    if (i == 0) vn0 = v; else if (i == 1) vn1 = v; else vn2 = v;
                }
            }
        }
        __syncthreads();
        if (w < 10) {
            #pragma unroll
            for (int tt = 0; tt < 5; ++tt) {
                short8 bh = *(const short8*)&Bhi[(tt * 64 + l) * 8];
                short8 bl = *(const short8*)&Blo[(tt * 64 + l) * 8];
                f32x4 a = (tt == 0) ? acc0 : (tt == 1) ? acc1 : (tt == 2) ? acc2 : (tt == 3) ? acc3 : acc4;
                a = __builtin_amdgcn_mfma_f32_16x16x32_bf16(Ahi[fc], bh, a, 0, 0, 0);
                a = __builtin_amdgcn_mfma_f32_16x16x32_bf16(Ahi[fc], bl, a, 0, 0, 0);
                a = __builtin_amdgcn_mfma_f32_16x16x32_bf16(Alo[fc], bh, a, 0, 0, 0);
                if (tt == 0) acc0 = a; else if (tt == 1) acc1 = a; else if (tt == 2) acc2 = a;
                else if (tt == 3) acc3 = a; else acc4 = a;
            }
        }
        __syncthreads();   // fragments consumed; safe to overwrite next iter
        vcur0 = vn0; vcur1 = vn1; vcur2 = vn2;
    }

    // ---- LN stats (red arrays alias Qlds region, which is garbage so far) ----
    float qlbv[4], gam[4], bet[4];
    if (w < 10) {
        #pragma unroll
        for (int r = 0; r < 4; ++r) {
            int fo = 16 * w + kb * 4 + r;
            qlbv[r] = qlb[fo];
            float sq = 1.f / (1.f + expf(-qvec[fo]));
            gam[r] = qng[fo] * sq;
            bet[r] = qnb[fo] * sq;
        }
        #pragma unroll
        for (int tt = 0; tt < 5; ++tt) {
            f32x4 a = (tt == 0) ? acc0 : (tt == 1) ? acc1 : (tt == 2) ? acc2 : (tt == 3) ? acc3 : acc4;
            float v0 = a[0] + qlbv[0], v1 = a[1] + qlbv[1];
            float v2 = a[2] + qlbv[2], v3 = a[3] + qlbv[3];
            int j = tt * 16 + row;
            redS[j * 41 + w * 4 + kb] = v0 + v1 + v2 + v3;
            redQ[j * 41 + w * 4 + kb] = v0 * v0 + v1 * v1 + v2 * v2 + v3 * v3;
        }
    }
    __syncthreads();

    if (tid < 80) {
        float s = 0.f, q = 0.f;
        #pragma unroll 8
        for (int j = 0; j < 40; ++j) {
            s += redS[tid * 41 + j];
            q += redQ[tid * 41 + j];
        }
        float mean = s * (1.f / NF);
        float var = q * (1.f / NF) - mean * mean;
        lnM[tid] = mean;
        lnI[tid] = 1.f / sqrtf(var + 1e-5f);
    }
    __syncthreads();

    if (w < 10) {
        #pragma unroll
        for (int tt = 0; tt < 5; ++tt) {
            f32x4 a = (tt == 0) ? acc0 : (tt == 1) ? acc1 : (tt == 2) ? acc2 : (tt == 3) ? acc3 : acc4;
            int j = tt * 16 + row;
            float mean = lnM[j], inv = lnI[j];
            #pragma unroll
            for (int r = 0; r < 4; ++r) {
                int fo = 16 * w + kb * 4 + r;
                float v = a[r] + qlbv[r];
                Qlds[fo * QSTR + j] = (v - mean) * inv * gam[r] + bet[r];
            }
        }
    }
    __syncthreads();   // Qlds ready

    // ---- phase 3: folded key pipeline + scores (wave w: f in [10w,10w+10)) ----
    float alpha[4], beta4[4], gamm[4], G[4], H[4];
    {
        float M0[4], M1[4], B4[4];
        #pragma unroll
        for (int jo = 0; jo < 4; ++jo) {
            float m0 = 0.f, m1 = 0.f, bb = klb[jo];
            #pragma unroll
            for (int ji = 0; ji < 4; ++ji) {
                float kl = klw[jo * 4 + ji];
                m0 = fmaf(kl, kcw[(4 * c + ji) * 2 + 0], m0);
                m1 = fmaf(kl, kcw[(4 * c + ji) * 2 + 1], m1);
                bb = fmaf(kl, kcb[4 * c + ji], bb);
            }
            M0[jo] = m0; M1[jo] = m1; B4[jo] = bb;
        }
        float am = 0.25f * (M0[0] + M0[1] + M0[2] + M0[3]);
        float bm = 0.25f * (M1[0] + M1[1] + M1[2] + M1[3]);
        float cm = 0.25f * (B4[0] + B4[1] + B4[2] + B4[3]);
        #pragma unroll
        for (int jo = 0; jo < 4; ++jo) {
            alpha[jo] = M0[jo] - am;
            beta4[jo] = M1[jo] - bm;
            gamm[jo]  = B4[jo] - cm;
            float sk = 0.5f / (1.f + expf(-kvec[jo]));   // sigmoid/sqrt(k)
            G[jo] = kng[jo] * sk;
            H[jo] = knb[jo] * sk;
        }
    }

    const int t = t0 + l;
    const bool valid = t < NT;

    float s[16];
    #pragma unroll
    for (int x = 0; x < 16; ++x) s[x] = 0.f;

    const float* mix0 = mix + (size_t)(b * 2) * NF * NT;
    const float* mix1 = mix0 + (size_t)NF * NT;
    const int f0 = w * 10;

    if (valid) {
        #pragma unroll
        for (int ff = 0; ff < 10; ++ff) {
            int f = f0 + ff;
            float m0 = mix0[(size_t)f * NT + t];
            float m1 = mix1[(size_t)f * NT + t];
            float d0 = fmaf(alpha[0], m0, fmaf(beta4[0], m1, gamm[0]));
            float d1 = fmaf(alpha[1], m0, fmaf(beta4[1], m1, gamm[1]));
            float d2 = fmaf(alpha[2], m0, fmaf(beta4[2], m1, gamm[2]));
            float d3 = fmaf(alpha[3], m0, fmaf(beta4[3], m1, gamm[3]));
            float var = 0.25f * (d0 * d0 + d1 * d1 + d2 * d2 + d3 * d3);
            float inv = 1.f / sqrtf(var + 1e-5f);
            float kn[4];
            kn[0] = fmaf(d0 * inv, G[0], H[0]);
            kn[1] = fmaf(d1 * inv, G[1], H[1]);
            kn[2] = fmaf(d2 * inv, G[2], H[2]);
            kn[3] = fmaf(d3 * inv, G[3], H[3]);

            float q0 = Qlds[f * QSTR + l + 0];
            float q1 = Qlds[f * QSTR + l + 1];
            float q2 = Qlds[f * QSTR + l + 2];
            float q3 = Qlds[f * QSTR + l + 3];
            #pragma unroll
            for (int j = 0; j < 4; ++j) {
                s[0 * 4 + j] = fmaf(q0, kn[j], s[0 * 4 + j]);
                s[1 * 4 + j] = fmaf(q1, kn[j], s[1 * 4 + j]);
                s[2 * 4 + j] = fmaf(q2, kn[j], s[2 * 4 + j]);
                s[3 * 4 + j] = fmaf(q3, kn[j], s[3 * 4 + j]);
            }
        }
    }
    __syncthreads();   // all Qlds reads done before sbuf overwrites pool

    // park partials: sbuf[(w*64+l)*17 + x]
    {
        float* dst = &sbuf[(w * 64 + l) * 17];
        #pragma unroll
        for (int q4 = 0; q4 < 4; ++q4) {
            float4 v = {s[q4 * 4 + 0], s[q4 * 4 + 1], s[q4 * 4 + 2], s[q4 * 4 + 3]};
            *(float4*)(dst + q4 * 4) = v;
        }
    }
    __syncthreads();

    // ---- phase 4: reduce 16 groups + quadrant softmax + W write ----
    if (tid < 256) {
        int q4 = tid >> 6;
        int ln = tid & 63;
        int tt = t0 + ln;
        if (tt < NT) {
            float4 a = *(const float4*)&sbuf[(0 * 64 + ln) * 17 + q4 * 4];
            #pragma unroll
            for (int ww = 1; ww < 16; ++ww) {
                float4 p = *(const float4*)&sbuf[(ww * 64 + ln) * 17 + q4 * 4];
                a.x += p.x; a.y += p.y; a.z += p.z; a.w += p.w;
            }
            float mx = fmaxf(fmaxf(a.x, a.y), fmaxf(a.z, a.w));
            float e0 = expf(a.x - mx), e1 = expf(a.y - mx);
            float e2 = expf(a.z - mx), e3 = expf(a.w - mx);
            float inv = 1.f / (e0 + e1 + e2 + e3);
            float4 v = {e0 * inv, e1 * inv, e2 * inv, e3 * inv};
            *(float4*)(W + ((size_t)bc * NT + tt) * 16 + q4 * 4) = v;
        }
    }
}

// ---------------------------------------------------------------------------
// complex 4x4 solve, partial pivoting (cabs1), fully unrolled
// ---------------------------------------------------------------------------
__device__ __forceinline__ void csolve4(float Ar[16], float Ai[16],
                                        float br[4], float bi[4],
                                        float wr[4], float wi[4]) {
    #pragma unroll
    for (int col = 0; col < 4; ++col) {
        #pragma unroll
        for (int r = col + 1; r < 4; ++r) {
            float cp = fabsf(Ar[col * 4 + col]) + fabsf(Ai[col * 4 + col]);
            float cr = fabsf(Ar[r * 4 + col]) + fabsf(Ai[r * 4 + col]);
            bool sw = cr > cp;
            #pragma unroll
            for (int m = col; m < 4; ++m) {
                float a0 = Ar[col * 4 + m], a1 = Ar[r * 4 + m];
                Ar[col * 4 + m] = sw ? a1 : a0;
                Ar[r * 4 + m]   = sw ? a0 : a1;
                float c0 = Ai[col * 4 + m], c1 = Ai[r * 4 + m];
                Ai[col * 4 + m] = sw ? c1 : c0;
                Ai[r * 4 + m]   = sw ? c0 : c1;
            }
            float b0 = br[col], b1 = br[r];
            br[col] = sw ? b1 : b0; br[r] = sw ? b0 : b1;
            float d0 = bi[col], d1 = bi[r];
            bi[col] = sw ? d1 : d0; bi[r] = sw ? d0 : d1;
        }
        float pr = Ar[col * 4 + col], pi = Ai[col * 4 + col];
        float den = 1.f / (pr * pr + pi * pi);
        #pragma unroll
        for (int r = col + 1; r < 4; ++r) {
            float nr = Ar[r * 4 + col], ni = Ai[r * 4 + col];
            float fr = (nr * pr + ni * pi) * den;
            float fi = (ni * pr - nr * pi) * den;
            #pragma unroll
            for (int m = col + 1; m < 4; ++m) {
                float tr = Ar[col * 4 + m], ti = Ai[col * 4 + m];
                Ar[r * 4 + m] -= fr * tr - fi * ti;
                Ai[r * 4 + m] -= fr * ti + fi * tr;
            }
            float tr = br[col], ti = bi[col];
            br[r] -= fr * tr - fi * ti;
            bi[r] -= fr * ti + fi * tr;
        }
    }
    #pragma unroll
    for (int col = 3; col >= 0; --col) {
        float sr = br[col], si = bi[col];
        #pragma unroll
        for (int m = col + 1; m < 4; ++m) {
            float tr = Ar[col * 4 + m], ti = Ai[col * 4 + m];
            sr -= tr * wr[m] - ti * wi[m];
            si -= tr * wi[m] + ti * wr[m];
        }
        float pr = Ar[col * 4 + col], pi = Ai[col * 4 + col];
        float den = 1.f / (pr * pr + pi * pi);
        wr[col] = (sr * pr + si * pi) * den;
        wi[col] = (si * pr - sr * pi) * den;
    }
}

// ---------------------------------------------------------------------------
// k4: per (b,f,t): build rank-1 value/out, assemble A,rhs, solve, Wiener sum
// ---------------------------------------------------------------------------
__global__ __launch_bounds__(256) void k4_final(const float* __restrict__ far,
                                                const float* __restrict__ mix,
                                                const float* __restrict__ Wt,
                                                const float* __restrict__ vvec,
                                                float* __restrict__ out) {
    const int t = blockIdx.x * 256 + threadIdx.x;
    const int f = blockIdx.y;
    const int b = blockIdx.z;
    if (t >= NT) return;

    const float* fr  = far + (size_t)(b * 2 + 0) * NF * NT + (size_t)f * NT;
    const float* fim = far + (size_t)(b * 2 + 1) * NF * NT + (size_t)f * NT;
    float ur[4], ui[4];
    #pragma unroll
    for (int d = 0; d < 4; ++d) {
        int tp = t - 3 + d;
        bool ok = tp >= 0;
        ur[d] = ok ? fr[tp] : 0.f;
        ui[d] = ok ? fim[tp] : 0.f;
    }
    float m0 = mix[(size_t)(b * 2 + 0) * NF * NT + (size_t)f * NT + t];
    float m1 = mix[(size_t)(b * 2 + 1) * NF * NT + (size_t)f * NT + t];

    float sv[4];
    #pragma unroll
    for (int i = 0; i < 4; ++i) sv[i] = 1.f / (1.f + expf(-vvec[i]));

    const float* w0p = Wt + ((size_t)(b * 2 + 0) * NT + t) * 16;
    const float* w1p = Wt + ((size_t)(b * 2 + 1) * NT + t) * 16;

    float g0[4], g1[4];
    #pragma unroll
    for (int j = 0; j < 4; ++j) { g0[j] = 0.f; g1[j] = 0.f; }
    #pragma unroll
    for (int i = 0; i < 4; ++i) {
        float a0 = ur[i] * sv[i];
        float a1 = -ui[i] * sv[i];
        #pragma unroll
        for (int j = 0; j < 4; ++j) {
            g0[j] = fmaf(a0, w0p[i * 4 + j], g0[j]);
            g1[j] = fmaf(a1, w1p[i * 4 + j], g1[j]);
        }
    }

    float Ar[16], Ai[16], br[4], bi[4], wr[4], wi[4];
    #pragma unroll
    for (int j = 0; j < 4; ++j) {
        #pragma unroll
        for (int m = 0; m < 4; ++m) {
            float e = (j == m) ? (1.0f + 1e-8f) : 1e-8f;
            Ar[j * 4 + m] = fmaf(ur[m], g0[j], e);
            Ai[j * 4 + m] = fmaf(-ui[m], g1[j], e);
        }
        br[j] = m0 * g0[j];
        bi[j] = m1 * g1[j];
    }

    csolve4(Ar, Ai, br, bi, wr, wi);

    float resr = 0.f, resi = 0.f;
    #pragma unroll
    for (int d = 0; d < 4; ++d) {
        resr += ur[d] * wr[d] - ui[d] * wi[d];
        resi += ur[d] * wi[d] + ui[d] * wr[d];
    }
    out[(size_t)(b * 2 + 0) * NF * NT + (size_t)f * NT + t] = resr;
    out[(size_t)(b * 2 + 1) * NF * NT + (size_t)f * NT + t] = resi;
}

// ---------------------------------------------------------------------------
extern "C" void kernel_launch(void* const* d_in, const int* in_sizes, int n_in,
                              void* d_out, int out_size, void* d_ws, size_t ws_size,
                              hipStream_t stream) {
    const float* far  = (const float*)d_in[0];
    const float* mix  = (const float*)d_in[1];
    const float* kcw  = (const float*)d_in[2];
    const float* kcb  = (const float*)d_in[3];
    const float* qlw  = (const float*)d_in[4];
    const float* qlb  = (const float*)d_in[5];
    const float* qng  = (const float*)d_in[6];
    const float* qnb  = (const float*)d_in[7];
    const float* klw  = (const float*)d_in[8];
    const float* klb  = (const float*)d_in[9];
    const float* kng  = (const float*)d_in[10];
    const float* knb  = (const float*)d_in[11];
    const float* qvec = (const float*)d_in[12];
    const float* kvec = (const float*)d_in[13];
    const float* vvec = (const float*)d_in[14];

    float* W = (float*)d_ws;                 // 16*1000*16 floats
    float* out = (float*)d_out;

    k13_fused<<<dim3(NBC, (NT + TS - 1) / TS), 1024, 0, stream>>>(
        far, mix, qlw, qlb, qng, qnb, qvec, kcw, kcb, klw, klb, kng, knb, kvec, W);
    k4_final<<<dim3(4, NF, 8), 256, 0, stream>>>(far, mix, W, vvec, out);
}